// Round 10
// baseline (652.276 us; speedup 1.0000x reference)
//
#include <hip/hip_runtime.h>
#include <math.h>

// ---------------------------------------------------------------------------
// BinAlexNet forward — round 10: barrier-free stats epilogues (per-wave part
// slots), CO=8 channel blocking on conv2/3/4, single-chunk K (conv4 NWC=6,
// conv5 NWC=4). Zero-correction + weight-zero fallback kept from round 9.
// ---------------------------------------------------------------------------

typedef unsigned long long u64;

__device__ __forceinline__ float sgn(float x) {
    return (float)((x > 0.0f) - (x < 0.0f));
}

__device__ __forceinline__ void wred_i(int& s, long long& q) {
    #pragma unroll
    for (int o = 32; o > 0; o >>= 1) {
        s += __shfl_down(s, o, 64);
        q += __shfl_down(q, o, 64);
    }
}
__device__ __forceinline__ void wred_d(double& s, double& q) {
    #pragma unroll
    for (int o = 32; o > 0; o >>= 1) {
        s += __shfl_down(s, o, 64);
        q += __shfl_down(q, o, 64);
    }
}

// wflags slots: 0:conv2 1:conv3 2:conv4 3:conv5 4:fc1 5:fc2 6:fc3
// ---------------------------------------------------------------------------
__device__ void pack_conv_one(int idx, const float* __restrict__ w,
                              u64* __restrict__ wp, int Cout, int Cin, int KK,
                              int* flag) {
    int NW = (Cin + 63) >> 6;
    int wd = idx % NW, t = idx / NW;
    int tap = t % KK, co = t / KK;
    u64 s = 0, nz = 0;
    for (int c = 0; c < 64; ++c) {
        int ci = wd * 64 + c;
        if (ci >= Cin) break;
        float v = w[((size_t)co * Cin + ci) * KK + tap];
        if (v > 0.0f) s |= (1ull << c);
        if (v != 0.0f) nz |= (1ull << c);
    }
    u64* o = wp + ((size_t)co * KK + tap) * 2 * NW + 2 * wd;
    o[0] = s; o[1] = nz;
    if (nz != ~0ull) atomicOr(flag, 1);
}

__device__ void pack_fc_one(int idx, const float* __restrict__ w,
                            u64* __restrict__ ws_, u64* __restrict__ wn_,
                            int Kd, int* flag) {
    int NW = Kd >> 6;
    int wd = idx % NW, o = idx / NW;
    const float* row = w + (size_t)o * Kd + wd * 64;
    u64 s = 0, nz = 0;
    for (int c = 0; c < 64; ++c) {
        float v = row[c];
        if (v > 0.0f) s |= (1ull << c);
        if (v != 0.0f) nz |= (1ull << c);
    }
    ws_[(size_t)o * NW + wd] = s;
    wn_[(size_t)o * NW + wd] = nz;
    if (nz != ~0ull) atomicOr(flag, 1);
}

#define PN0 4800
#define PN1 4800
#define PN2 10368
#define PN3 13824
#define PN4 9216
#define PN5 65536
#define PN6 131072
#define PN7 320
#define PREP_TOTAL (PN0+PN1+PN2+PN3+PN4+PN5+PN6+PN7)   // 239936

__global__ void k_prep(const float* w1, float* w1s,
                       const float* w2, u64* w2p,
                       const float* w3, u64* w3p,
                       const float* w4, u64* w4p,
                       const float* w5, u64* w5p,
                       const float* wl1, u64* wl1s_, u64* wl1n_,
                       const float* wl2, u64* wl2s_, u64* wl2n_,
                       const float* wl3, u64* wl3s_, u64* wl3n_,
                       int* wflags) {
    int idx = blockIdx.x * blockDim.x + threadIdx.x;
    int r = idx;
    if (r < PN0) { w1s[r] = sgn(w1[r]); return; } r -= PN0;
    if (r < PN1) { pack_conv_one(r, w2, w2p, 192, 64, 25, wflags + 0); return; } r -= PN1;
    if (r < PN2) { pack_conv_one(r, w3, w3p, 384, 192, 9, wflags + 1); return; } r -= PN2;
    if (r < PN3) { pack_conv_one(r, w4, w4p, 256, 384, 9, wflags + 2); return; } r -= PN3;
    if (r < PN4) { pack_conv_one(r, w5, w5p, 256, 256, 9, wflags + 3); return; } r -= PN4;
    if (r < PN5) { pack_fc_one(r, wl1, wl1s_, wl1n_, 1024, wflags + 4); return; } r -= PN5;
    if (r < PN6) { pack_fc_one(r, wl2, wl2s_, wl2n_, 4096, wflags + 5); return; } r -= PN6;
    if (r < PN7) { pack_fc_one(r, wl3, wl3s_, wl3n_, 2048, wflags + 6); return; }
}

// ---------------------------------------------------------------------------
__device__ void prefix3(const u64* __restrict__ wb, int NW, ushort* __restrict__ o) {
    int cs[9];
    #pragma unroll
    for (int tap = 0; tap < 9; ++tap) {
        int s = 0;
        for (int wd = 0; wd < NW; ++wd)
            s += (int)__popcll(wb[tap * 2 * NW + 2 * wd]);
        cs[tap] = s;
    }
    int P[4][4];
    P[0][0] = 0; P[0][1] = 0; P[0][2] = 0; P[0][3] = 0;
    P[1][0] = 0; P[2][0] = 0; P[3][0] = 0;
    P[1][1] = cs[0];                 P[1][2] = cs[0] + cs[1];                 P[1][3] = cs[0] + cs[1] + cs[2];
    P[2][1] = cs[0] + cs[3];         P[2][2] = cs[0] + cs[1] + cs[3] + cs[4]; P[2][3] = P[1][3] + cs[3] + cs[4] + cs[5];
    P[3][1] = cs[0] + cs[3] + cs[6]; P[3][2] = P[2][2] + cs[6] + cs[7];       P[3][3] = P[2][3] + cs[6] + cs[7] + cs[8];
    #pragma unroll
    for (int i = 0; i < 4; ++i)
        #pragma unroll
        for (int j = 0; j < 4; ++j)
            o[i * 4 + j] = (ushort)P[i][j];
}

__global__ void k_prep2(const u64* w2p, const u64* w3p, const u64* w4p, const u64* w5p,
                        ushort* t2, ushort* t3, ushort* t4, ushort* t5) {
    int idx = blockIdx.x * blockDim.x + threadIdx.x;
    if (idx < 192) {
        const u64* wb = w2p + idx * 50;
        int cnt[25];
        #pragma unroll
        for (int tap = 0; tap < 25; ++tap) cnt[tap] = (int)__popcll(wb[tap * 2]);
        int R1 = 0, C1 = 0;
        #pragma unroll
        for (int k = 0; k < 5; ++k) { R1 += cnt[k]; C1 += cnt[k * 5]; }
        t2[idx * 4 + 0] = (ushort)R1;
        t2[idx * 4 + 1] = (ushort)C1;
        t2[idx * 4 + 2] = (ushort)cnt[0];
        t2[idx * 4 + 3] = 0;
        return;
    }
    idx -= 192;
    if (idx < 384) { prefix3(w3p + (size_t)idx * 54, 3, t3 + idx * 16); return; }
    idx -= 384;
    if (idx < 256) { prefix3(w4p + (size_t)idx * 108, 6, t4 + idx * 16); return; }
    idx -= 256;
    if (idx < 256) { prefix3(w5p + (size_t)idx * 72, 4, t5 + idx * 16); return; }
}

// ---------------------------------------------------------------------------
// conv1: fp32, LDS image, fused pool + per-wave stats (no epilogue barriers).
// part slot: c*2048 + b*4 + wid
// ---------------------------------------------------------------------------
__global__ __launch_bounds__(256)
void k_conv1(const float* __restrict__ x, const float* __restrict__ w1s,
             float* __restrict__ out, double* __restrict__ part) {
    __shared__ float sx[3 * 34 * 34];
    const int b = blockIdx.y, cg = blockIdx.x, t = threadIdx.x;
    for (int i = t; i < 3 * 34 * 34; i += 256) sx[i] = 0.0f;
    __syncthreads();
    for (int i = t; i < 3072; i += 256) {
        int ch = i >> 10, rem = i & 1023, yy = rem >> 5, xx = rem & 31;
        sx[(ch * 34 + yy + 1) * 34 + xx + 1] = x[(size_t)b * 3072 + i];
    }
    __syncthreads();
    const bool act = t < 225;
    const int py = act ? t / 15 : 0, px = act ? t % 15 : 0;
    float a0[8], a1[8], a2[8], a3[8];
    #pragma unroll
    for (int c = 0; c < 8; ++c) { a0[c] = a1[c] = a2[c] = a3[c] = 0.f; }
    #pragma unroll 1
    for (int ch = 0; ch < 3; ++ch) {
        const float* wc = w1s + (size_t)(cg * 8) * 75 + ch * 25;
        #pragma unroll 1
        for (int yy6 = 0; yy6 < 6; ++yy6) {
            const float2* rp = (const float2*)&sx[(ch * 34 + py * 2 + yy6) * 34 + px * 2];
            float2 ra = rp[0], rb = rp[1], rc = rp[2];
            float r[6] = {ra.x, ra.y, rb.x, rb.y, rc.x, rc.y};
            if (yy6 <= 4) {
                #pragma unroll
                for (int kx = 0; kx < 5; ++kx)
                    #pragma unroll
                    for (int cc = 0; cc < 8; ++cc) {
                        float wv = wc[cc * 75 + yy6 * 5 + kx];
                        a0[cc] = fmaf(r[kx],     wv, a0[cc]);
                        a1[cc] = fmaf(r[kx + 1], wv, a1[cc]);
                    }
            }
            if (yy6 >= 1) {
                #pragma unroll
                for (int kx = 0; kx < 5; ++kx)
                    #pragma unroll
                    for (int cc = 0; cc < 8; ++cc) {
                        float wv = wc[cc * 75 + (yy6 - 1) * 5 + kx];
                        a2[cc] = fmaf(r[kx],     wv, a2[cc]);
                        a3[cc] = fmaf(r[kx + 1], wv, a3[cc]);
                    }
            }
        }
    }
    const int wid = t >> 6, lane = t & 63;
    #pragma unroll
    for (int cc = 0; cc < 8; ++cc) {
        float best = 0.f;
        if (act) {
            best = fmaxf(fmaxf(a0[cc], a1[cc]), fmaxf(a2[cc], a3[cc]));
            out[((size_t)b * 64 + cg * 8 + cc) * 225 + t] = best;
        }
        double v = act ? (double)best : 0.0;
        double q = v * v;
        wred_d(v, q);
        if (lane == 0) {
            size_t slot = (size_t)(cg * 8 + cc) * 2048 + b * 4 + wid;
            part[slot * 2]     = v;
            part[slot * 2 + 1] = q;
        }
    }
}

// ---------------------------------------------------------------------------
// conv2 (K=5, NW=1) + maxpool2x2. CO=8, per-wave stats. grid (24, 64).
// part slot: c*320 + bg*5 + wid
// ---------------------------------------------------------------------------
__global__ __launch_bounds__(320)
void k_conv2(const u64* __restrict__ ps, const u64* __restrict__ zap,
             const u64* __restrict__ w, float* __restrict__ out,
             double* __restrict__ part, const ushort* __restrict__ t2,
             const int* __restrict__ wflags, const int* __restrict__ bz) {
    __shared__ u64 st_s[8 * 17 * 17];
    __shared__ int sbz[8];
    const int co0 = blockIdx.x * 8, bg = blockIdx.y, b0 = bg * 8, t = threadIdx.x;
    const int wfl = wflags[0];
    if (t < 8) sbz[t] = bz[b0 + t];
    for (int i = t; i < 8 * 289; i += 320) st_s[i] = 0;
    __syncthreads();
    for (int i = t; i < 8 * 225; i += 320) {
        int bb = i / 225, j = i - bb * 225;
        int yy = j / 15, xx = j - yy * 15;
        st_s[(bb * 17 + yy + 1) * 17 + xx + 1] = ps[(size_t)(b0 + bb) * 225 + j];
    }
    __syncthreads();
    const bool act = t < 288;
    const int bb = act ? t / 36 : 0, r = act ? t - (t / 36) * 36 : 0;
    const int py = r / 6, px = r - py * 6;
    int best[8];
    #pragma unroll
    for (int cc = 0; cc < 8; ++cc) best[cc] = 0;
    if (act) {
        if (wfl == 0) {
            int S0[8], S1[8], S2[8], S3[8];
            #pragma unroll
            for (int cc = 0; cc < 8; ++cc) { S0[cc] = S1[cc] = S2[cc] = S3[cc] = 0; }
            #pragma unroll 1
            for (int yy6 = 0; yy6 < 6; ++yy6) {
                const int base = (bb * 17 + py * 2 + yy6) * 17 + px * 2;
                u64 V[6];
                #pragma unroll
                for (int k = 0; k < 6; ++k) V[k] = st_s[base + k];
                if (yy6 <= 4) {
                    #pragma unroll
                    for (int kx = 0; kx < 5; ++kx) {
                        #pragma unroll
                        for (int cc = 0; cc < 8; ++cc) {
                            u64 ws_ = w[(size_t)(co0 + cc) * 50 + (yy6 * 5 + kx) * 2];
                            S0[cc] += (int)__popcll(V[kx] ^ ws_);
                            S1[cc] += (int)__popcll(V[kx + 1] ^ ws_);
                        }
                    }
                }
                if (yy6 >= 1) {
                    #pragma unroll
                    for (int kx = 0; kx < 5; ++kx) {
                        #pragma unroll
                        for (int cc = 0; cc < 8; ++cc) {
                            u64 ws_ = w[(size_t)(co0 + cc) * 50 + ((yy6 - 1) * 5 + kx) * 2];
                            S2[cc] += (int)__popcll(V[kx] ^ ws_);
                            S3[cc] += (int)__popcll(V[kx + 1] ^ ws_);
                        }
                    }
                }
            }
            int C0[8], C1[8], C2[8], C3[8];
            #pragma unroll
            for (int cc = 0; cc < 8; ++cc) { C0[cc] = C1[cc] = C2[cc] = C3[cc] = 0; }
            if (sbz[bb]) {
                #pragma unroll 1
                for (int dy = 0; dy < 2; ++dy)
                #pragma unroll 1
                for (int dx = 0; dx < 2; ++dx) {
                    int yc = py * 2 + dy, xc = px * 2 + dx;
                    #pragma unroll 1
                    for (int ky = 0; ky < 5; ++ky) {
                        int yy = yc - 1 + ky;
                        if ((unsigned)yy >= 15u) continue;
                        #pragma unroll 1
                        for (int kx = 0; kx < 5; ++kx) {
                            int xx = xc - 1 + kx;
                            if ((unsigned)xx >= 15u) continue;
                            u64 za = zap[(size_t)(b0 + bb) * 225 + yy * 15 + xx];
                            if (za) {
                                int pz = (int)__popcll(za);
                                #pragma unroll
                                for (int cc = 0; cc < 8; ++cc) {
                                    u64 ws_ = w[(size_t)(co0 + cc) * 50 + (ky * 5 + kx) * 2];
                                    int d = 2 * (int)__popcll(ws_ & za) - pz;
                                    if (dy == 0 && dx == 0) C0[cc] += d;
                                    else if (dy == 0)       C1[cc] += d;
                                    else if (dx == 0)       C2[cc] += d;
                                    else                    C3[cc] += d;
                                }
                            }
                        }
                    }
                }
            }
            const int py0 = (py == 0), px0 = (px == 0);
            #pragma unroll
            for (int cc = 0; cc < 8; ++cc) {
                const ushort* tb = t2 + (co0 + cc) * 4;
                const int R1 = tb[0], C1v = tb[1], X = tb[2];
                int d0 = 64 * (5 - py0) * (5 - px0) - 2 * S0[cc] + 2 * (py0 * R1 + px0 * C1v - py0 * px0 * X) + C0[cc];
                int d1 = 64 * (5 - py0) * 5 - 2 * S1[cc] + 2 * (py0 * R1) + C1[cc];
                int d2 = 64 * 5 * (5 - px0) - 2 * S2[cc] + 2 * (px0 * C1v) + C2[cc];
                int d3 = 1600 - 2 * S3[cc] + C3[cc];
                best[cc] = max(max(d0, d1), max(d2, d3));
            }
        } else {
            #pragma unroll 1
            for (int cc = 0; cc < 8; ++cc) {
                const u64* wb = w + (size_t)(co0 + cc) * 50;
                int bst = -1000000;
                for (int dy = 0; dy < 2; ++dy)
                    for (int dx = 0; dx < 2; ++dx) {
                        int yc = py * 2 + dy, xc = px * 2 + dx;
                        int sum = 0;
                        for (int ky = 0; ky < 5; ++ky) {
                            int yy = yc - 1 + ky;
                            if ((unsigned)yy >= 15u) continue;
                            for (int kx = 0; kx < 5; ++kx) {
                                int xx = xc - 1 + kx;
                                if ((unsigned)xx >= 15u) continue;
                                size_t g = (size_t)(b0 + bb) * 225 + yy * 15 + xx;
                                u64 val = ~zap[g] & wb[(ky * 5 + kx) * 2 + 1];
                                u64 df  = (ps[g] ^ wb[(ky * 5 + kx) * 2]) & val;
                                sum += (int)__popcll(val) - 2 * (int)__popcll(df);
                            }
                        }
                        bst = max(bst, sum);
                    }
                best[cc] = bst;
            }
        }
        #pragma unroll
        for (int cc = 0; cc < 8; ++cc)
            out[((size_t)(b0 + bb) * 192 + co0 + cc) * 36 + r] = (float)best[cc];
    }
    const int wid = t >> 6, lane = t & 63;
    #pragma unroll
    for (int cc = 0; cc < 8; ++cc) {
        int v = act ? best[cc] : 0;
        long long q = (long long)v * v;
        wred_i(v, q);
        if (lane == 0) {
            size_t slot = (size_t)(co0 + cc) * 320 + bg * 5 + wid;
            part[slot * 2]     = (double)v;
            part[slot * 2 + 1] = (double)q;
        }
    }
}

// ---------------------------------------------------------------------------
// 3x3 pad-1 binary conv on 6x6 (conv3/conv4). CO=8, single-chunk, per-wave
// stats. grid (Cout/8, 64).
// ---------------------------------------------------------------------------
template<int NW, int NWC>
__global__ __launch_bounds__(320)
void k_convbin3(const u64* __restrict__ ps, const u64* __restrict__ zap,
                const u64* __restrict__ w, float* __restrict__ out,
                double* __restrict__ part, int Cout,
                const ushort* __restrict__ tP, const int* __restrict__ wflags,
                int slot, const int* __restrict__ bz) {
    __shared__ u64 st_s[NWC * 576];
    __shared__ int sbz[8];
    const int co0 = blockIdx.x * 8, bg = blockIdx.y, b0 = bg * 8, t = threadIdx.x;
    const int wfl = wflags[slot];
    if (t < 8) sbz[t] = bz[b0 + t];
    const bool act = t < 288;
    const int bb = act ? t / 36 : 0, r = act ? t - (t / 36) * 36 : 0;
    const int y = r / 6, x0 = r - y * 6;
    int S[8];
    #pragma unroll
    for (int cc = 0; cc < 8; ++cc) S[cc] = 0;
    #pragma unroll 1
    for (int c0 = 0; c0 < NW; c0 += NWC) {
        __syncthreads();
        for (int i = t; i < NWC * 576; i += 320) st_s[i] = 0;
        __syncthreads();
        for (int i = t; i < 8 * 36 * NWC; i += 320) {
            int wd = i % NWC, j = (i / NWC) % 36, bb2 = i / (36 * NWC);
            int yy = j / 6, xx = j - yy * 6;
            st_s[wd * 576 + bb2 * 72 + (yy + 1) * 9 + xx + 1] =
                ps[((size_t)(b0 + bb2) * 36 + j) * NW + c0 + wd];
        }
        __syncthreads();
        if (act && wfl == 0) {
            #pragma unroll
            for (int ky = 0; ky < 3; ++ky)
                #pragma unroll
                for (int kx = 0; kx < 3; ++kx) {
                    const int vb = bb * 72 + (y + ky) * 9 + x0 + kx;
                    #pragma unroll
                    for (int wd = 0; wd < NWC; ++wd) {
                        u64 a = st_s[wd * 576 + vb];
                        #pragma unroll
                        for (int cc = 0; cc < 8; ++cc) {
                            u64 ws_ = w[((size_t)(co0 + cc) * 9 + ky * 3 + kx) * 2 * NW + 2 * (c0 + wd)];
                            S[cc] += (int)__popcll(a ^ ws_);
                        }
                    }
                }
        }
    }
    int sv[8];
    if (wfl == 0) {
        const int ky0 = (y == 0), ky1 = (y == 5) ? 2 : 3;
        const int kx0 = (x0 == 0), kx1 = (x0 == 5) ? 2 : 3;
        const int nv = (ky1 - ky0) * (kx1 - kx0);
        #pragma unroll
        for (int cc = 0; cc < 8; ++cc) {
            const ushort* tb = tP + (co0 + cc) * 16;
            int Wt = tb[15];
            int Wr = (int)tb[ky1 * 4 + kx1] - (int)tb[ky0 * 4 + kx1]
                   - (int)tb[ky1 * 4 + kx0] + (int)tb[ky0 * 4 + kx0];
            sv[cc] = 64 * NW * nv - 2 * S[cc] + 2 * (Wt - Wr);
        }
        if (act && sbz[bb]) {
            #pragma unroll 1
            for (int ky = 0; ky < 3; ++ky) {
                int yy = y - 1 + ky;
                if ((unsigned)yy >= 6u) continue;
                #pragma unroll 1
                for (int kx = 0; kx < 3; ++kx) {
                    int xx = x0 - 1 + kx;
                    if ((unsigned)xx >= 6u) continue;
                    size_t g = ((size_t)(b0 + bb) * 36 + yy * 6 + xx) * NW;
                    #pragma unroll 1
                    for (int wd = 0; wd < NW; ++wd) {
                        u64 za = zap[g + wd];
                        if (za) {
                            int pz = (int)__popcll(za);
                            #pragma unroll
                            for (int cc = 0; cc < 8; ++cc) {
                                u64 ws_ = w[((size_t)(co0 + cc) * 9 + ky * 3 + kx) * 2 * NW + 2 * wd];
                                sv[cc] += 2 * (int)__popcll(ws_ & za) - pz;
                            }
                        }
                    }
                }
            }
        }
    } else {
        #pragma unroll 1
        for (int cc = 0; cc < 8; ++cc) {
            int sum = 0;
            if (act) {
                const u64* wb = w + (size_t)(co0 + cc) * 9 * 2 * NW;
                for (int ky = 0; ky < 3; ++ky) {
                    int yy = y - 1 + ky;
                    if ((unsigned)yy >= 6u) continue;
                    for (int kx = 0; kx < 3; ++kx) {
                        int xx = x0 - 1 + kx;
                        if ((unsigned)xx >= 6u) continue;
                        size_t g = ((size_t)(b0 + bb) * 36 + yy * 6 + xx) * NW;
                        const u64* wp = wb + (ky * 3 + kx) * 2 * NW;
                        for (int wd = 0; wd < NW; ++wd) {
                            u64 val = ~zap[g + wd] & wp[2 * wd + 1];
                            u64 df  = (ps[g + wd] ^ wp[2 * wd]) & val;
                            sum += (int)__popcll(val) - 2 * (int)__popcll(df);
                        }
                    }
                }
            }
            sv[cc] = sum;
        }
    }
    if (act) {
        #pragma unroll
        for (int cc = 0; cc < 8; ++cc)
            out[((size_t)(b0 + bb) * Cout + co0 + cc) * 36 + r] = (float)sv[cc];
    }
    const int wid = t >> 6, lane = t & 63;
    #pragma unroll
    for (int cc = 0; cc < 8; ++cc) {
        int v = act ? sv[cc] : 0;
        long long q = (long long)v * v;
        wred_i(v, q);
        if (lane == 0) {
            size_t pslot = (size_t)(co0 + cc) * 320 + bg * 5 + wid;
            part[pslot * 2]     = (double)v;
            part[pslot * 2 + 1] = (double)q;
        }
    }
}

// ---------------------------------------------------------------------------
// conv5 (NW=4, single chunk) + in-LDS maxpool3x3/2 + per-wave stats on POOLED.
// CO=4. grid (64, 64).
// ---------------------------------------------------------------------------
__global__ __launch_bounds__(320)
void k_conv5(const u64* __restrict__ ps, const u64* __restrict__ zap,
             const u64* __restrict__ w, float* __restrict__ outp,
             double* __restrict__ part, const ushort* __restrict__ tP,
             const int* __restrict__ wflags, const int* __restrict__ bz) {
    __shared__ u64 st_s[4 * 576];
    __shared__ int sacc[4][288];
    __shared__ int sbz[8];
    const int co0 = blockIdx.x * 4, bg = blockIdx.y, b0 = bg * 8, t = threadIdx.x;
    const int wfl = wflags[3];
    if (t < 8) sbz[t] = bz[b0 + t];
    const bool act = t < 288;
    const int bb = act ? t / 36 : 0, r = act ? t - (t / 36) * 36 : 0;
    const int y = r / 6, x0 = r - y * 6;
    for (int i = t; i < 4 * 576; i += 320) st_s[i] = 0;
    __syncthreads();
    for (int i = t; i < 8 * 36 * 4; i += 320) {
        int wd = i % 4, j = (i / 4) % 36, bb2 = i / 144;
        int yy = j / 6, xx = j - yy * 6;
        st_s[wd * 576 + bb2 * 72 + (yy + 1) * 9 + xx + 1] =
            ps[((size_t)(b0 + bb2) * 36 + j) * 4 + wd];
    }
    __syncthreads();
    int S[4] = {0, 0, 0, 0};
    if (act && wfl == 0) {
        #pragma unroll
        for (int ky = 0; ky < 3; ++ky)
            #pragma unroll
            for (int kx = 0; kx < 3; ++kx) {
                const int vb = bb * 72 + (y + ky) * 9 + x0 + kx;
                #pragma unroll
                for (int wd = 0; wd < 4; ++wd) {
                    u64 a = st_s[wd * 576 + vb];
                    #pragma unroll
                    for (int cc = 0; cc < 4; ++cc) {
                        u64 ws_ = w[((size_t)(co0 + cc) * 9 + ky * 3 + kx) * 8 + 2 * wd];
                        S[cc] += (int)__popcll(a ^ ws_);
                    }
                }
            }
    }
    if (act) {
        int sv[4];
        if (wfl == 0) {
            const int ky0 = (y == 0), ky1 = (y == 5) ? 2 : 3;
            const int kx0 = (x0 == 0), kx1 = (x0 == 5) ? 2 : 3;
            const int nv = (ky1 - ky0) * (kx1 - kx0);
            #pragma unroll
            for (int cc = 0; cc < 4; ++cc) {
                const ushort* tb = tP + (co0 + cc) * 16;
                int Wt = tb[15];
                int Wr = (int)tb[ky1 * 4 + kx1] - (int)tb[ky0 * 4 + kx1]
                       - (int)tb[ky1 * 4 + kx0] + (int)tb[ky0 * 4 + kx0];
                sv[cc] = 256 * nv - 2 * S[cc] + 2 * (Wt - Wr);
            }
            if (sbz[bb]) {
                #pragma unroll 1
                for (int ky = 0; ky < 3; ++ky) {
                    int yy = y - 1 + ky;
                    if ((unsigned)yy >= 6u) continue;
                    #pragma unroll 1
                    for (int kx = 0; kx < 3; ++kx) {
                        int xx = x0 - 1 + kx;
                        if ((unsigned)xx >= 6u) continue;
                        size_t g = ((size_t)(b0 + bb) * 36 + yy * 6 + xx) * 4;
                        #pragma unroll 1
                        for (int wd = 0; wd < 4; ++wd) {
                            u64 za = zap[g + wd];
                            if (za) {
                                int pz = (int)__popcll(za);
                                #pragma unroll
                                for (int cc = 0; cc < 4; ++cc) {
                                    u64 ws_ = w[((size_t)(co0 + cc) * 9 + ky * 3 + kx) * 8 + 2 * wd];
                                    sv[cc] += 2 * (int)__popcll(ws_ & za) - pz;
                                }
                            }
                        }
                    }
                }
            }
        } else {
            #pragma unroll 1
            for (int cc = 0; cc < 4; ++cc) {
                const u64* wb = w + (size_t)(co0 + cc) * 72;
                int sum = 0;
                for (int ky = 0; ky < 3; ++ky) {
                    int yy = y - 1 + ky;
                    if ((unsigned)yy >= 6u) continue;
                    for (int kx = 0; kx < 3; ++kx) {
                        int xx = x0 - 1 + kx;
                        if ((unsigned)xx >= 6u) continue;
                        size_t g = ((size_t)(b0 + bb) * 36 + yy * 6 + xx) * 4;
                        const u64* wp = wb + (ky * 3 + kx) * 8;
                        for (int wd = 0; wd < 4; ++wd) {
                            u64 val = ~zap[g + wd] & wp[2 * wd + 1];
                            u64 df  = (ps[g + wd] ^ wp[2 * wd]) & val;
                            sum += (int)__popcll(val) - 2 * (int)__popcll(df);
                        }
                    }
                }
                sv[cc] = sum;
            }
        }
        #pragma unroll
        for (int cc = 0; cc < 4; ++cc)
            sacc[cc][bb * 36 + r] = sv[cc];
    }
    __syncthreads();
    int pooled[4] = {0, 0, 0, 0};
    const bool pact = t < 32;
    if (pact) {
        int bb2 = t / 4, wi = t % 4, py = (wi >> 1) * 2, px = (wi & 1) * 2;
        #pragma unroll
        for (int cc = 0; cc < 4; ++cc) {
            int best = -1000000;
            #pragma unroll
            for (int dy = 0; dy < 3; ++dy)
                #pragma unroll
                for (int dx = 0; dx < 3; ++dx)
                    best = max(best, sacc[cc][bb2 * 36 + (py + dy) * 6 + (px + dx)]);
            pooled[cc] = best;
            outp[((size_t)(b0 + bb2) * 256 + co0 + cc) * 4 + wi] = (float)best;
        }
    }
    const int wid = t >> 6, lane = t & 63;
    #pragma unroll
    for (int cc = 0; cc < 4; ++cc) {
        int v = pact ? pooled[cc] : 0;
        long long q = (long long)v * v;
        wred_i(v, q);
        if (lane == 0) {
            size_t pslot = (size_t)(co0 + cc) * 320 + bg * 5 + wid;
            part[pslot * 2]     = (double)v;
            part[pslot * 2 + 1] = (double)q;
        }
    }
}

// ---------------------------------------------------------------------------
__global__ void k_stats_final(const double* __restrict__ part, const float* __restrict__ g,
                              float* __restrict__ mean, float* __restrict__ inva,
                              int NB, long total) {
    __shared__ double sS[64], sQ[64];
    const int c = blockIdx.x, t = threadIdx.x;
    double s = 0.0, q = 0.0;
    for (int k = t; k < NB; k += 64) {
        s += part[((size_t)c * NB + k) * 2];
        q += part[((size_t)c * NB + k) * 2 + 1];
    }
    sS[t] = s; sQ[t] = q;
    __syncthreads();
    for (int o = 32; o > 0; o >>= 1) {
        if (t < o) { sS[t] += sS[t + o]; sQ[t] += sQ[t + o]; }
        __syncthreads();
    }
    if (t == 0) {
        double m = sS[0] / (double)total;
        double var = sQ[0] / (double)total - m * m;
        mean[c] = (float)m;
        inva[c] = g[c] * (float)(1.0 / sqrt(var + 1e-5));
    }
}

// ---- BN apply + sign + pack -> sign plane, za plane, per-batch zero flags ----
__global__ void k_bnpack2d(const float* __restrict__ x, const float* __restrict__ m,
                           const float* __restrict__ a, const float* __restrict__ bt,
                           u64* __restrict__ ps, u64* __restrict__ za,
                           int B, int C, int HW, int* __restrict__ bz) {
    int NW = C >> 6;
    int tot = B * HW * NW;
    int idx = blockIdx.x * blockDim.x + threadIdx.x;
    if (idx >= tot) return;
    int wd = idx % NW, t = idx / NW;
    int j = t % HW, b = t / HW;
    u64 s = 0, nz = 0;
    for (int c0 = 0; c0 < 64; ++c0) {
        int c = wd * 64 + c0;
        float v = (x[((size_t)b * C + c) * HW + j] - m[c]) * a[c] + bt[c];
        if (v > 0.0f) s |= (1ull << c0);
        if (v != 0.0f) nz |= (1ull << c0);
    }
    size_t o = ((size_t)b * HW + j) * NW + wd;
    ps[o] = s; za[o] = ~nz;
    if (nz != ~0ull) atomicOr(bz + b, 1);
}

__global__ void k_bnpack_flat(const float* __restrict__ x, const float* __restrict__ m,
                              const float* __restrict__ a, const float* __restrict__ bt,
                              u64* __restrict__ ps, u64* __restrict__ za,
                              int B, int* __restrict__ bz) {
    int idx = blockIdx.x * blockDim.x + threadIdx.x;
    if (idx >= B * 16) return;
    int wd = idx % 16, b = idx / 16;
    u64 s = 0, nz = 0;
    for (int k = 0; k < 64; ++k) {
        int f = wd * 64 + k;
        int c = f >> 2, j = f & 3;
        float v = (x[((size_t)b * 256 + c) * 4 + j] - m[c]) * a[c] + bt[c];
        if (v > 0.0f) s |= (1ull << k);
        if (v != 0.0f) nz |= (1ull << k);
    }
    ps[(size_t)b * 16 + wd] = s;
    za[(size_t)b * 16 + wd] = ~nz;
    if (nz != ~0ull) atomicOr(bz + b, 1);
}

__global__ void k_bnpack1d(const float* __restrict__ x, const float* __restrict__ m,
                           const float* __restrict__ a, const float* __restrict__ bt,
                           u64* __restrict__ ps, u64* __restrict__ za,
                           int B, int F, int* __restrict__ bz) {
    int NW = F >> 6;
    int idx = blockIdx.x * blockDim.x + threadIdx.x;
    if (idx >= B * NW) return;
    int wd = idx % NW, b = idx / NW;
    const float* row = x + (size_t)b * F + wd * 64;
    u64 s = 0, nz = 0;
    for (int c = 0; c < 64; ++c) {
        int f = wd * 64 + c;
        float v = (row[c] - m[f]) * a[f] + bt[f];
        if (v > 0.0f) s |= (1ull << c);
        if (v != 0.0f) nz |= (1ull << c);
    }
    ps[(size_t)b * NW + wd] = s;
    za[(size_t)b * NW + wd] = ~nz;
    if (nz != ~0ull) atomicOr(bz + b, 1);
}

// ---------------------------------------------------------------------------
// binary FC, 32x32 tile, 2x2 micro-tile, sign-only LDS, row zero-correction.
// ---------------------------------------------------------------------------
template<int NW>
__global__ __launch_bounds__(256)
void k_fcbin3(const u64* __restrict__ As_, const u64* __restrict__ zaA,
              const u64* __restrict__ Ws_, const u64* __restrict__ Wn_,
              const float* __restrict__ bias, float* __restrict__ C, int O,
              double* __restrict__ part, int nbc, const int* __restrict__ wflags,
              int slot, const int* __restrict__ rowz) {
    constexpr int ST = NW | 1;
    __shared__ u64 sA[32 * ST];
    __shared__ u64 sW[32 * ST];
    __shared__ int sacc[32][32];
    __shared__ int srz[32];
    const int t = threadIdx.x;
    const int wfl = wflags[slot];
    const int b0 = blockIdx.y * 32, o0 = blockIdx.x * 32;
    if (t < 32) srz[t] = rowz[b0 + t];
    for (int i = t; i < 32 * NW; i += 256) {
        int rr = i / NW, cc = i % NW;
        sA[rr * ST + cc] = As_[(size_t)(b0 + rr) * NW + cc];
        int o = o0 + rr;
        sW[rr * ST + cc] = (o < O) ? Ws_[(size_t)o * NW + cc] : 0ull;
    }
    __syncthreads();
    const int tx = t % 16, ty = t / 16;
    int acc[2][2];
    if (wfl == 0) {
        int S00 = 0, S01 = 0, S10 = 0, S11 = 0;
        #pragma unroll
        for (int wd = 0; wd < NW; ++wd) {
            u64 a0 = sA[ty * ST + wd], a1 = sA[(16 + ty) * ST + wd];
            u64 w0 = sW[tx * ST + wd], w1 = sW[(16 + tx) * ST + wd];
            S00 += (int)__popcll(a0 ^ w0); S01 += (int)__popcll(a0 ^ w1);
            S10 += (int)__popcll(a1 ^ w0); S11 += (int)__popcll(a1 ^ w1);
        }
        acc[0][0] = 64 * NW - 2 * S00; acc[0][1] = 64 * NW - 2 * S01;
        acc[1][0] = 64 * NW - 2 * S10; acc[1][1] = 64 * NW - 2 * S11;
        #pragma unroll
        for (int i = 0; i < 2; ++i) {
            if (srz[ty + 16 * i]) {
                int b = b0 + ty + 16 * i;
                int c0_ = 0, c1_ = 0;
                #pragma unroll 1
                for (int wd = 0; wd < NW; ++wd) {
                    u64 za = zaA[(size_t)b * NW + wd];
                    if (za) {
                        int pz = (int)__popcll(za);
                        c0_ += 2 * (int)__popcll(sW[tx * ST + wd] & za) - pz;
                        c1_ += 2 * (int)__popcll(sW[(16 + tx) * ST + wd] & za) - pz;
                    }
                }
                acc[i][0] += c0_;
                acc[i][1] += c1_;
            }
        }
    } else {
        #pragma unroll 1
        for (int i = 0; i < 2; ++i)
            #pragma unroll 1
            for (int j = 0; j < 2; ++j) {
                int b = b0 + ty + 16 * i, o = o0 + tx + 16 * j;
                int aV = 0, aD = 0;
                if (o < O) {
                    for (int wd = 0; wd < NW; ++wd) {
                        u64 val = ~zaA[(size_t)b * NW + wd] & Wn_[(size_t)o * NW + wd];
                        u64 df  = (As_[(size_t)b * NW + wd] ^ Ws_[(size_t)o * NW + wd]) & val;
                        aV += (int)__popcll(val); aD += (int)__popcll(df);
                    }
                }
                acc[i][j] = aV - 2 * aD;
            }
    }
    #pragma unroll
    for (int i = 0; i < 2; ++i)
        #pragma unroll
        for (int j = 0; j < 2; ++j) {
            int o = o0 + tx + 16 * j;
            int v = (o < O) ? acc[i][j] : 0;
            if (o < O)
                C[(size_t)(b0 + ty + 16 * i) * O + o] = (float)v + (bias ? bias[o] : 0.0f);
            sacc[ty + 16 * i][tx + 16 * j] = v;
        }
    __syncthreads();
    if (part != nullptr && t < 32) {
        int s = 0; long long q = 0;
        #pragma unroll
        for (int b = 0; b < 32; ++b) {
            int v = sacc[b][t];
            s += v; q += (long long)v * v;
        }
        if (o0 + t < O) {
            part[((size_t)(o0 + t) * nbc + blockIdx.y) * 2]     = (double)s;
            part[((size_t)(o0 + t) * nbc + blockIdx.y) * 2 + 1] = (double)q;
        }
    }
}

// ---------------------------------------------------------------------------

static inline int cdiv(long a, int b) { return (int)((a + b - 1) / b); }

extern "C" void kernel_launch(void* const* d_in, const int* in_sizes, int n_in,
                              void* d_out, int out_size, void* d_ws, size_t ws_size,
                              hipStream_t stream) {
    const float* x   = (const float*)d_in[0];
    const float* w1  = (const float*)d_in[1];
    const float* g1  = (const float*)d_in[2];
    const float* b1  = (const float*)d_in[3];
    const float* w2  = (const float*)d_in[4];
    const float* g2  = (const float*)d_in[5];
    const float* b2  = (const float*)d_in[6];
    const float* w3  = (const float*)d_in[7];
    const float* g3  = (const float*)d_in[8];
    const float* b3  = (const float*)d_in[9];
    const float* w4  = (const float*)d_in[10];
    const float* g4  = (const float*)d_in[11];
    const float* b4  = (const float*)d_in[12];
    const float* w5  = (const float*)d_in[13];
    const float* g5  = (const float*)d_in[14];
    const float* b5  = (const float*)d_in[15];
    const float* wl1 = (const float*)d_in[16];
    const float* gl1 = (const float*)d_in[17];
    const float* bl1 = (const float*)d_in[18];
    const float* wl2 = (const float*)d_in[19];
    const float* gl2 = (const float*)d_in[20];
    const float* bl2 = (const float*)d_in[21];
    const float* wl3 = (const float*)d_in[22];
    const float* bl3 = (const float*)d_in[23];
    float* out = (float*)d_out;
    (void)in_sizes; (void)n_in; (void)out_size; (void)ws_size;

    char* base = (char*)d_ws;
    size_t off = 0;
    auto alloc = [&](size_t bytes) {
        char* p = base + off;
        off += (bytes + 15) & ~(size_t)15;
        return (void*)p;
    };
    float* R1   = (float*)alloc(7372800 * 4);
    float* R2   = (float*)alloc(4718592 * 4);
    float* R3   = (float*)alloc(524288 * 4);
    float* w1s  = (float*)alloc(4800 * 4);
    u64* p1s = (u64*)alloc(115200 * 8);   u64* p1z = (u64*)alloc(115200 * 8);
    u64* p2s = (u64*)alloc(55296 * 8);    u64* p2z = (u64*)alloc(55296 * 8);
    u64* p3s = (u64*)alloc(110592 * 8);   u64* p3z = (u64*)alloc(110592 * 8);
    u64* p4s = (u64*)alloc(73728 * 8);    u64* p4z = (u64*)alloc(73728 * 8);
    u64* p5s = (u64*)alloc(8192 * 8);     u64* p5z = (u64*)alloc(8192 * 8);
    u64* pf1s = (u64*)alloc(32768 * 8);   u64* pf1z = (u64*)alloc(32768 * 8);
    u64* pf2s = (u64*)alloc(16384 * 8);   u64* pf2z = (u64*)alloc(16384 * 8);
    u64* w2p  = (u64*)alloc(9600 * 8);
    u64* w3p  = (u64*)alloc(20736 * 8);
    u64* w4p  = (u64*)alloc(27648 * 8);
    u64* w5p  = (u64*)alloc(18432 * 8);
    u64* wl1s_ = (u64*)alloc(65536 * 8);  u64* wl1n_ = (u64*)alloc(65536 * 8);
    u64* wl2s_ = (u64*)alloc(131072 * 8); u64* wl2n_ = (u64*)alloc(131072 * 8);
    u64* wl3s_ = (u64*)alloc(320 * 8);    u64* wl3n_ = (u64*)alloc(320 * 8);
    double* part = (double*)alloc((size_t)131072 * 2 * 8);   // max: conv1 64ch x 2048 slots
    float* stats = (float*)alloc(7 * 2 * 4096 * 4);
    int* wflags = (int*)alloc((8 + 7 * 512) * 4);
    int* bzc2 = wflags + 8;
    int* bzc3 = bzc2 + 512;
    int* bzc4 = bzc3 + 512;
    int* bzc5 = bzc4 + 512;
    int* rz1  = bzc5 + 512;
    int* rz2  = rz1 + 512;
    int* rz3  = rz2 + 512;
    ushort* t2 = (ushort*)alloc(192 * 4 * 2);
    ushort* t3 = (ushort*)alloc(384 * 16 * 2);
    ushort* t4 = (ushort*)alloc(256 * 16 * 2);
    ushort* t5 = (ushort*)alloc(256 * 16 * 2);
    float* m_[7]; float* a_[7];
    for (int l = 0; l < 7; ++l) { m_[l] = stats + (size_t)l * 8192; a_[l] = m_[l] + 4096; }

    hipMemsetAsync(wflags, 0, (8 + 7 * 512) * 4, stream);

    // ---- weight prep ----
    k_prep<<<cdiv(PREP_TOTAL, 256), 256, 0, stream>>>(
        w1, w1s, w2, w2p, w3, w3p, w4, w4p, w5, w5p,
        wl1, wl1s_, wl1n_, wl2, wl2s_, wl2n_, wl3, wl3s_, wl3n_, wflags);
    k_prep2<<<cdiv(192 + 384 + 256 + 256, 256), 256, 0, stream>>>(
        w2p, w3p, w4p, w5p, t2, t3, t4, t5);

    // ---- conv1 + pool -> R1 (+stats); bn1; pack -> p1 ----
    k_conv1<<<dim3(8, 512), 256, 0, stream>>>(x, w1s, R1, part);
    k_stats_final<<<64, 64, 0, stream>>>(part, g1, m_[0], a_[0], 2048, (long)512 * 225);
    k_bnpack2d<<<cdiv((long)512 * 225, 256), 256, 0, stream>>>(R1, m_[0], a_[0], b1, p1s, p1z, 512, 64, 225, bzc2);

    // ---- conv2 (CO=8) + pool -> R2 (+stats); bn2; pack -> p2 ----
    k_conv2<<<dim3(24, 64), 320, 0, stream>>>(p1s, p1z, w2p, R2, part, t2, wflags, bzc2);
    k_stats_final<<<192, 64, 0, stream>>>(part, g2, m_[1], a_[1], 320, (long)512 * 36);
    k_bnpack2d<<<cdiv((long)512 * 36 * 3, 256), 256, 0, stream>>>(R2, m_[1], a_[1], b2, p2s, p2z, 512, 192, 36, bzc3);

    // ---- conv3 (CO=8) -> R1 (+stats); bn3; pack -> p3 ----
    k_convbin3<3, 3><<<dim3(48, 64), 320, 0, stream>>>(p2s, p2z, w3p, R1, part, 384, t3, wflags, 1, bzc3);
    k_stats_final<<<384, 64, 0, stream>>>(part, g3, m_[2], a_[2], 320, (long)512 * 36);
    k_bnpack2d<<<cdiv((long)512 * 36 * 6, 256), 256, 0, stream>>>(R1, m_[2], a_[2], b3, p3s, p3z, 512, 384, 36, bzc4);

    // ---- conv4 (CO=8, single chunk NWC=6) -> R2 (+stats); bn4; pack -> p4 ----
    k_convbin3<6, 6><<<dim3(32, 64), 320, 0, stream>>>(p3s, p3z, w4p, R2, part, 256, t4, wflags, 2, bzc4);
    k_stats_final<<<256, 64, 0, stream>>>(part, g4, m_[3], a_[3], 320, (long)512 * 36);
    k_bnpack2d<<<cdiv((long)512 * 36 * 4, 256), 256, 0, stream>>>(R2, m_[3], a_[3], b4, p4s, p4z, 512, 256, 36, bzc5);

    // ---- conv5 (CO=4, single chunk) + in-LDS pool -> R3 (+stats); bn5; pack -> p5 ----
    k_conv5<<<dim3(64, 64), 320, 0, stream>>>(p4s, p4z, w5p, R3, part, t5, wflags, bzc5);
    k_stats_final<<<256, 64, 0, stream>>>(part, g5, m_[4], a_[4], 320, (long)512 * 4);
    k_bnpack_flat<<<cdiv(512 * 16, 256), 256, 0, stream>>>(R3, m_[4], a_[4], b5, p5s, p5z, 512, rz1);

    // ---- fc1 -> R2 (+stats); bn; pack -> pf1 ----
    k_fcbin3<16><<<dim3(128, 16), 256, 0, stream>>>(p5s, p5z, wl1s_, wl1n_, nullptr, R2, 4096, part, 16, wflags, 4, rz1);
    k_stats_final<<<4096, 64, 0, stream>>>(part, gl1, m_[5], a_[5], 16, 512);
    k_bnpack1d<<<cdiv(512 * 64, 256), 256, 0, stream>>>(R2, m_[5], a_[5], bl1, pf1s, pf1z, 512, 4096, rz2);

    // ---- fc2 -> R1 (+stats); bn; pack -> pf2 ----
    k_fcbin3<64><<<dim3(64, 16), 256, 0, stream>>>(pf1s, pf1z, wl2s_, wl2n_, nullptr, R1, 2048, part, 16, wflags, 5, rz2);
    k_stats_final<<<2048, 64, 0, stream>>>(part, gl2, m_[6], a_[6], 16, 512);
    k_bnpack1d<<<cdiv(512 * 32, 256), 256, 0, stream>>>(R1, m_[6], a_[6], bl2, pf2s, pf2z, 512, 2048, rz3);

    // ---- fc3 + bias -> out [512,10] ----
    k_fcbin3<32><<<dim3(1, 16), 256, 0, stream>>>(pf2s, pf2z, wl3s_, wl3n_, bl3, out, 10, nullptr, 0, wflags, 6, rz3);
}

// Round 11
// 586.995 us; speedup vs baseline: 1.1112x; 1.1112x over previous
//
#include <hip/hip_runtime.h>
#include <math.h>

// ---------------------------------------------------------------------------
// BinAlexNet forward — round 11: r9 compute structure (CO=4 channel blocking,
// machine-filling grids) + r10's barrier-free per-wave stats epilogues +
// single-chunk conv4 (NWC=6) / conv5 (NWC=4). Sparse zero-correction and
// weight-zero fallback unchanged from r9.
// ---------------------------------------------------------------------------

typedef unsigned long long u64;

__device__ __forceinline__ float sgn(float x) {
    return (float)((x > 0.0f) - (x < 0.0f));
}

__device__ __forceinline__ void wred_i(int& s, long long& q) {
    #pragma unroll
    for (int o = 32; o > 0; o >>= 1) {
        s += __shfl_down(s, o, 64);
        q += __shfl_down(q, o, 64);
    }
}
__device__ __forceinline__ void wred_d(double& s, double& q) {
    #pragma unroll
    for (int o = 32; o > 0; o >>= 1) {
        s += __shfl_down(s, o, 64);
        q += __shfl_down(q, o, 64);
    }
}

// wflags slots: 0:conv2 1:conv3 2:conv4 3:conv5 4:fc1 5:fc2 6:fc3
// ---------------------------------------------------------------------------
__device__ void pack_conv_one(int idx, const float* __restrict__ w,
                              u64* __restrict__ wp, int Cout, int Cin, int KK,
                              int* flag) {
    int NW = (Cin + 63) >> 6;
    int wd = idx % NW, t = idx / NW;
    int tap = t % KK, co = t / KK;
    u64 s = 0, nz = 0;
    for (int c = 0; c < 64; ++c) {
        int ci = wd * 64 + c;
        if (ci >= Cin) break;
        float v = w[((size_t)co * Cin + ci) * KK + tap];
        if (v > 0.0f) s |= (1ull << c);
        if (v != 0.0f) nz |= (1ull << c);
    }
    u64* o = wp + ((size_t)co * KK + tap) * 2 * NW + 2 * wd;
    o[0] = s; o[1] = nz;
    if (nz != ~0ull) atomicOr(flag, 1);
}

__device__ void pack_fc_one(int idx, const float* __restrict__ w,
                            u64* __restrict__ ws_, u64* __restrict__ wn_,
                            int Kd, int* flag) {
    int NW = Kd >> 6;
    int wd = idx % NW, o = idx / NW;
    const float* row = w + (size_t)o * Kd + wd * 64;
    u64 s = 0, nz = 0;
    for (int c = 0; c < 64; ++c) {
        float v = row[c];
        if (v > 0.0f) s |= (1ull << c);
        if (v != 0.0f) nz |= (1ull << c);
    }
    ws_[(size_t)o * NW + wd] = s;
    wn_[(size_t)o * NW + wd] = nz;
    if (nz != ~0ull) atomicOr(flag, 1);
}

#define PN0 4800
#define PN1 4800
#define PN2 10368
#define PN3 13824
#define PN4 9216
#define PN5 65536
#define PN6 131072
#define PN7 320
#define PREP_TOTAL (PN0+PN1+PN2+PN3+PN4+PN5+PN6+PN7)   // 239936

__global__ void k_prep(const float* w1, float* w1s,
                       const float* w2, u64* w2p,
                       const float* w3, u64* w3p,
                       const float* w4, u64* w4p,
                       const float* w5, u64* w5p,
                       const float* wl1, u64* wl1s_, u64* wl1n_,
                       const float* wl2, u64* wl2s_, u64* wl2n_,
                       const float* wl3, u64* wl3s_, u64* wl3n_,
                       int* wflags) {
    int idx = blockIdx.x * blockDim.x + threadIdx.x;
    int r = idx;
    if (r < PN0) { w1s[r] = sgn(w1[r]); return; } r -= PN0;
    if (r < PN1) { pack_conv_one(r, w2, w2p, 192, 64, 25, wflags + 0); return; } r -= PN1;
    if (r < PN2) { pack_conv_one(r, w3, w3p, 384, 192, 9, wflags + 1); return; } r -= PN2;
    if (r < PN3) { pack_conv_one(r, w4, w4p, 256, 384, 9, wflags + 2); return; } r -= PN3;
    if (r < PN4) { pack_conv_one(r, w5, w5p, 256, 256, 9, wflags + 3); return; } r -= PN4;
    if (r < PN5) { pack_fc_one(r, wl1, wl1s_, wl1n_, 1024, wflags + 4); return; } r -= PN5;
    if (r < PN6) { pack_fc_one(r, wl2, wl2s_, wl2n_, 4096, wflags + 5); return; } r -= PN6;
    if (r < PN7) { pack_fc_one(r, wl3, wl3s_, wl3n_, 2048, wflags + 6); return; }
}

// ---------------------------------------------------------------------------
__device__ void prefix3(const u64* __restrict__ wb, int NW, ushort* __restrict__ o) {
    int cs[9];
    #pragma unroll
    for (int tap = 0; tap < 9; ++tap) {
        int s = 0;
        for (int wd = 0; wd < NW; ++wd)
            s += (int)__popcll(wb[tap * 2 * NW + 2 * wd]);
        cs[tap] = s;
    }
    int P[4][4];
    P[0][0] = 0; P[0][1] = 0; P[0][2] = 0; P[0][3] = 0;
    P[1][0] = 0; P[2][0] = 0; P[3][0] = 0;
    P[1][1] = cs[0];                 P[1][2] = cs[0] + cs[1];                 P[1][3] = cs[0] + cs[1] + cs[2];
    P[2][1] = cs[0] + cs[3];         P[2][2] = cs[0] + cs[1] + cs[3] + cs[4]; P[2][3] = P[1][3] + cs[3] + cs[4] + cs[5];
    P[3][1] = cs[0] + cs[3] + cs[6]; P[3][2] = P[2][2] + cs[6] + cs[7];       P[3][3] = P[2][3] + cs[6] + cs[7] + cs[8];
    #pragma unroll
    for (int i = 0; i < 4; ++i)
        #pragma unroll
        for (int j = 0; j < 4; ++j)
            o[i * 4 + j] = (ushort)P[i][j];
}

__global__ void k_prep2(const u64* w2p, const u64* w3p, const u64* w4p, const u64* w5p,
                        ushort* t2, ushort* t3, ushort* t4, ushort* t5) {
    int idx = blockIdx.x * blockDim.x + threadIdx.x;
    if (idx < 192) {
        const u64* wb = w2p + idx * 50;
        int cnt[25];
        #pragma unroll
        for (int tap = 0; tap < 25; ++tap) cnt[tap] = (int)__popcll(wb[tap * 2]);
        int R1 = 0, C1 = 0;
        #pragma unroll
        for (int k = 0; k < 5; ++k) { R1 += cnt[k]; C1 += cnt[k * 5]; }
        t2[idx * 4 + 0] = (ushort)R1;
        t2[idx * 4 + 1] = (ushort)C1;
        t2[idx * 4 + 2] = (ushort)cnt[0];
        t2[idx * 4 + 3] = 0;
        return;
    }
    idx -= 192;
    if (idx < 384) { prefix3(w3p + (size_t)idx * 54, 3, t3 + idx * 16); return; }
    idx -= 384;
    if (idx < 256) { prefix3(w4p + (size_t)idx * 108, 6, t4 + idx * 16); return; }
    idx -= 256;
    if (idx < 256) { prefix3(w5p + (size_t)idx * 72, 4, t5 + idx * 16); return; }
}

// ---------------------------------------------------------------------------
// conv1: fp32, LDS image, fused pool + per-wave stats (no epilogue barriers).
// part slot: c*2048 + b*4 + wid
// ---------------------------------------------------------------------------
__global__ __launch_bounds__(256)
void k_conv1(const float* __restrict__ x, const float* __restrict__ w1s,
             float* __restrict__ out, double* __restrict__ part) {
    __shared__ float sx[3 * 34 * 34];
    const int b = blockIdx.y, cg = blockIdx.x, t = threadIdx.x;
    for (int i = t; i < 3 * 34 * 34; i += 256) sx[i] = 0.0f;
    __syncthreads();
    for (int i = t; i < 3072; i += 256) {
        int ch = i >> 10, rem = i & 1023, yy = rem >> 5, xx = rem & 31;
        sx[(ch * 34 + yy + 1) * 34 + xx + 1] = x[(size_t)b * 3072 + i];
    }
    __syncthreads();
    const bool act = t < 225;
    const int py = act ? t / 15 : 0, px = act ? t % 15 : 0;
    float a0[8], a1[8], a2[8], a3[8];
    #pragma unroll
    for (int c = 0; c < 8; ++c) { a0[c] = a1[c] = a2[c] = a3[c] = 0.f; }
    #pragma unroll 1
    for (int ch = 0; ch < 3; ++ch) {
        const float* wc = w1s + (size_t)(cg * 8) * 75 + ch * 25;
        #pragma unroll 1
        for (int yy6 = 0; yy6 < 6; ++yy6) {
            const float2* rp = (const float2*)&sx[(ch * 34 + py * 2 + yy6) * 34 + px * 2];
            float2 ra = rp[0], rb = rp[1], rc = rp[2];
            float r[6] = {ra.x, ra.y, rb.x, rb.y, rc.x, rc.y};
            if (yy6 <= 4) {
                #pragma unroll
                for (int kx = 0; kx < 5; ++kx)
                    #pragma unroll
                    for (int cc = 0; cc < 8; ++cc) {
                        float wv = wc[cc * 75 + yy6 * 5 + kx];
                        a0[cc] = fmaf(r[kx],     wv, a0[cc]);
                        a1[cc] = fmaf(r[kx + 1], wv, a1[cc]);
                    }
            }
            if (yy6 >= 1) {
                #pragma unroll
                for (int kx = 0; kx < 5; ++kx)
                    #pragma unroll
                    for (int cc = 0; cc < 8; ++cc) {
                        float wv = wc[cc * 75 + (yy6 - 1) * 5 + kx];
                        a2[cc] = fmaf(r[kx],     wv, a2[cc]);
                        a3[cc] = fmaf(r[kx + 1], wv, a3[cc]);
                    }
            }
        }
    }
    const int wid = t >> 6, lane = t & 63;
    #pragma unroll
    for (int cc = 0; cc < 8; ++cc) {
        float best = 0.f;
        if (act) {
            best = fmaxf(fmaxf(a0[cc], a1[cc]), fmaxf(a2[cc], a3[cc]));
            out[((size_t)b * 64 + cg * 8 + cc) * 225 + t] = best;
        }
        double v = act ? (double)best : 0.0;
        double q = v * v;
        wred_d(v, q);
        if (lane == 0) {
            size_t slot = (size_t)(cg * 8 + cc) * 2048 + b * 4 + wid;
            part[slot * 2]     = v;
            part[slot * 2 + 1] = q;
        }
    }
}

// ---------------------------------------------------------------------------
// conv2 (K=5, NW=1) + maxpool2x2. CO=4, per-wave stats. grid (48, 64).
// part slot: c*320 + bg*5 + wid
// ---------------------------------------------------------------------------
__global__ __launch_bounds__(320)
void k_conv2(const u64* __restrict__ ps, const u64* __restrict__ zap,
             const u64* __restrict__ w, float* __restrict__ out,
             double* __restrict__ part, const ushort* __restrict__ t2,
             const int* __restrict__ wflags, const int* __restrict__ bz) {
    __shared__ u64 st_s[8 * 17 * 17];
    __shared__ int sbz[8];
    const int co0 = blockIdx.x * 4, bg = blockIdx.y, b0 = bg * 8, t = threadIdx.x;
    const int wfl = wflags[0];
    if (t < 8) sbz[t] = bz[b0 + t];
    for (int i = t; i < 8 * 289; i += 320) st_s[i] = 0;
    __syncthreads();
    for (int i = t; i < 8 * 225; i += 320) {
        int bb = i / 225, j = i - bb * 225;
        int yy = j / 15, xx = j - yy * 15;
        st_s[(bb * 17 + yy + 1) * 17 + xx + 1] = ps[(size_t)(b0 + bb) * 225 + j];
    }
    __syncthreads();
    const bool act = t < 288;
    const int bb = act ? t / 36 : 0, r = act ? t - (t / 36) * 36 : 0;
    const int py = r / 6, px = r - py * 6;
    int best[4] = {0, 0, 0, 0};
    if (act) {
        if (wfl == 0) {
            int S0[4] = {0,0,0,0}, S1[4] = {0,0,0,0}, S2[4] = {0,0,0,0}, S3[4] = {0,0,0,0};
            #pragma unroll 1
            for (int yy6 = 0; yy6 < 6; ++yy6) {
                const int base = (bb * 17 + py * 2 + yy6) * 17 + px * 2;
                u64 V[6];
                #pragma unroll
                for (int k = 0; k < 6; ++k) V[k] = st_s[base + k];
                if (yy6 <= 4) {
                    #pragma unroll
                    for (int kx = 0; kx < 5; ++kx) {
                        #pragma unroll
                        for (int cc = 0; cc < 4; ++cc) {
                            u64 ws_ = w[(size_t)(co0 + cc) * 50 + (yy6 * 5 + kx) * 2];
                            S0[cc] += (int)__popcll(V[kx] ^ ws_);
                            S1[cc] += (int)__popcll(V[kx + 1] ^ ws_);
                        }
                    }
                }
                if (yy6 >= 1) {
                    #pragma unroll
                    for (int kx = 0; kx < 5; ++kx) {
                        #pragma unroll
                        for (int cc = 0; cc < 4; ++cc) {
                            u64 ws_ = w[(size_t)(co0 + cc) * 50 + ((yy6 - 1) * 5 + kx) * 2];
                            S2[cc] += (int)__popcll(V[kx] ^ ws_);
                            S3[cc] += (int)__popcll(V[kx + 1] ^ ws_);
                        }
                    }
                }
            }
            int C0[4] = {0,0,0,0}, C1[4] = {0,0,0,0}, C2[4] = {0,0,0,0}, C3[4] = {0,0,0,0};
            if (sbz[bb]) {
                #pragma unroll 1
                for (int dy = 0; dy < 2; ++dy)
                #pragma unroll 1
                for (int dx = 0; dx < 2; ++dx) {
                    int yc = py * 2 + dy, xc = px * 2 + dx;
                    #pragma unroll 1
                    for (int ky = 0; ky < 5; ++ky) {
                        int yy = yc - 1 + ky;
                        if ((unsigned)yy >= 15u) continue;
                        #pragma unroll 1
                        for (int kx = 0; kx < 5; ++kx) {
                            int xx = xc - 1 + kx;
                            if ((unsigned)xx >= 15u) continue;
                            u64 za = zap[(size_t)(b0 + bb) * 225 + yy * 15 + xx];
                            if (za) {
                                int pz = (int)__popcll(za);
                                #pragma unroll
                                for (int cc = 0; cc < 4; ++cc) {
                                    u64 ws_ = w[(size_t)(co0 + cc) * 50 + (ky * 5 + kx) * 2];
                                    int d = 2 * (int)__popcll(ws_ & za) - pz;
                                    if (dy == 0 && dx == 0) C0[cc] += d;
                                    else if (dy == 0)       C1[cc] += d;
                                    else if (dx == 0)       C2[cc] += d;
                                    else                    C3[cc] += d;
                                }
                            }
                        }
                    }
                }
            }
            const int py0 = (py == 0), px0 = (px == 0);
            #pragma unroll
            for (int cc = 0; cc < 4; ++cc) {
                const ushort* tb = t2 + (co0 + cc) * 4;
                const int R1 = tb[0], C1v = tb[1], X = tb[2];
                int d0 = 64 * (5 - py0) * (5 - px0) - 2 * S0[cc] + 2 * (py0 * R1 + px0 * C1v - py0 * px0 * X) + C0[cc];
                int d1 = 64 * (5 - py0) * 5 - 2 * S1[cc] + 2 * (py0 * R1) + C1[cc];
                int d2 = 64 * 5 * (5 - px0) - 2 * S2[cc] + 2 * (px0 * C1v) + C2[cc];
                int d3 = 1600 - 2 * S3[cc] + C3[cc];
                best[cc] = max(max(d0, d1), max(d2, d3));
            }
        } else {
            #pragma unroll 1
            for (int cc = 0; cc < 4; ++cc) {
                const u64* wb = w + (size_t)(co0 + cc) * 50;
                int bst = -1000000;
                for (int dy = 0; dy < 2; ++dy)
                    for (int dx = 0; dx < 2; ++dx) {
                        int yc = py * 2 + dy, xc = px * 2 + dx;
                        int sum = 0;
                        for (int ky = 0; ky < 5; ++ky) {
                            int yy = yc - 1 + ky;
                            if ((unsigned)yy >= 15u) continue;
                            for (int kx = 0; kx < 5; ++kx) {
                                int xx = xc - 1 + kx;
                                if ((unsigned)xx >= 15u) continue;
                                size_t g = (size_t)(b0 + bb) * 225 + yy * 15 + xx;
                                u64 val = ~zap[g] & wb[(ky * 5 + kx) * 2 + 1];
                                u64 df  = (ps[g] ^ wb[(ky * 5 + kx) * 2]) & val;
                                sum += (int)__popcll(val) - 2 * (int)__popcll(df);
                            }
                        }
                        bst = max(bst, sum);
                    }
                best[cc] = bst;
            }
        }
        #pragma unroll
        for (int cc = 0; cc < 4; ++cc)
            out[((size_t)(b0 + bb) * 192 + co0 + cc) * 36 + r] = (float)best[cc];
    }
    const int wid = t >> 6, lane = t & 63;
    #pragma unroll
    for (int cc = 0; cc < 4; ++cc) {
        int v = act ? best[cc] : 0;
        long long q = (long long)v * v;
        wred_i(v, q);
        if (lane == 0) {
            size_t slot = (size_t)(co0 + cc) * 320 + bg * 5 + wid;
            part[slot * 2]     = (double)v;
            part[slot * 2 + 1] = (double)q;
        }
    }
}

// ---------------------------------------------------------------------------
// 3x3 pad-1 binary conv on 6x6 (conv3/conv4). CO=4, per-wave stats.
// grid (Cout/4, 64), 320 thr.
// ---------------------------------------------------------------------------
template<int NW, int NWC>
__global__ __launch_bounds__(320)
void k_convbin3(const u64* __restrict__ ps, const u64* __restrict__ zap,
                const u64* __restrict__ w, float* __restrict__ out,
                double* __restrict__ part, int Cout,
                const ushort* __restrict__ tP, const int* __restrict__ wflags,
                int slot, const int* __restrict__ bz) {
    __shared__ u64 st_s[NWC * 576];
    __shared__ int sbz[8];
    const int co0 = blockIdx.x * 4, bg = blockIdx.y, b0 = bg * 8, t = threadIdx.x;
    const int wfl = wflags[slot];
    if (t < 8) sbz[t] = bz[b0 + t];
    const bool act = t < 288;
    const int bb = act ? t / 36 : 0, r = act ? t - (t / 36) * 36 : 0;
    const int y = r / 6, x0 = r - y * 6;
    int S[4] = {0, 0, 0, 0};
    #pragma unroll 1
    for (int c0 = 0; c0 < NW; c0 += NWC) {
        __syncthreads();
        for (int i = t; i < NWC * 576; i += 320) st_s[i] = 0;
        __syncthreads();
        for (int i = t; i < 8 * 36 * NWC; i += 320) {
            int wd = i % NWC, j = (i / NWC) % 36, bb2 = i / (36 * NWC);
            int yy = j / 6, xx = j - yy * 6;
            st_s[wd * 576 + bb2 * 72 + (yy + 1) * 9 + xx + 1] =
                ps[((size_t)(b0 + bb2) * 36 + j) * NW + c0 + wd];
        }
        __syncthreads();
        if (act && wfl == 0) {
            #pragma unroll
            for (int ky = 0; ky < 3; ++ky)
                #pragma unroll
                for (int kx = 0; kx < 3; ++kx) {
                    const int vb = bb * 72 + (y + ky) * 9 + x0 + kx;
                    #pragma unroll
                    for (int wd = 0; wd < NWC; ++wd) {
                        u64 a = st_s[wd * 576 + vb];
                        #pragma unroll
                        for (int cc = 0; cc < 4; ++cc) {
                            u64 ws_ = w[((size_t)(co0 + cc) * 9 + ky * 3 + kx) * 2 * NW + 2 * (c0 + wd)];
                            S[cc] += (int)__popcll(a ^ ws_);
                        }
                    }
                }
        }
    }
    int sv[4];
    if (wfl == 0) {
        const int ky0 = (y == 0), ky1 = (y == 5) ? 2 : 3;
        const int kx0 = (x0 == 0), kx1 = (x0 == 5) ? 2 : 3;
        const int nv = (ky1 - ky0) * (kx1 - kx0);
        #pragma unroll
        for (int cc = 0; cc < 4; ++cc) {
            const ushort* tb = tP + (co0 + cc) * 16;
            int Wt = tb[15];
            int Wr = (int)tb[ky1 * 4 + kx1] - (int)tb[ky0 * 4 + kx1]
                   - (int)tb[ky1 * 4 + kx0] + (int)tb[ky0 * 4 + kx0];
            sv[cc] = 64 * NW * nv - 2 * S[cc] + 2 * (Wt - Wr);
        }
        if (act && sbz[bb]) {
            #pragma unroll 1
            for (int ky = 0; ky < 3; ++ky) {
                int yy = y - 1 + ky;
                if ((unsigned)yy >= 6u) continue;
                #pragma unroll 1
                for (int kx = 0; kx < 3; ++kx) {
                    int xx = x0 - 1 + kx;
                    if ((unsigned)xx >= 6u) continue;
                    size_t g = ((size_t)(b0 + bb) * 36 + yy * 6 + xx) * NW;
                    #pragma unroll 1
                    for (int wd = 0; wd < NW; ++wd) {
                        u64 za = zap[g + wd];
                        if (za) {
                            int pz = (int)__popcll(za);
                            #pragma unroll
                            for (int cc = 0; cc < 4; ++cc) {
                                u64 ws_ = w[((size_t)(co0 + cc) * 9 + ky * 3 + kx) * 2 * NW + 2 * wd];
                                sv[cc] += 2 * (int)__popcll(ws_ & za) - pz;
                            }
                        }
                    }
                }
            }
        }
    } else {
        #pragma unroll 1
        for (int cc = 0; cc < 4; ++cc) {
            int sum = 0;
            if (act) {
                const u64* wb = w + (size_t)(co0 + cc) * 9 * 2 * NW;
                for (int ky = 0; ky < 3; ++ky) {
                    int yy = y - 1 + ky;
                    if ((unsigned)yy >= 6u) continue;
                    for (int kx = 0; kx < 3; ++kx) {
                        int xx = x0 - 1 + kx;
                        if ((unsigned)xx >= 6u) continue;
                        size_t g = ((size_t)(b0 + bb) * 36 + yy * 6 + xx) * NW;
                        const u64* wp = wb + (ky * 3 + kx) * 2 * NW;
                        for (int wd = 0; wd < NW; ++wd) {
                            u64 val = ~zap[g + wd] & wp[2 * wd + 1];
                            u64 df  = (ps[g + wd] ^ wp[2 * wd]) & val;
                            sum += (int)__popcll(val) - 2 * (int)__popcll(df);
                        }
                    }
                }
            }
            sv[cc] = sum;
        }
    }
    if (act) {
        #pragma unroll
        for (int cc = 0; cc < 4; ++cc)
            out[((size_t)(b0 + bb) * Cout + co0 + cc) * 36 + r] = (float)sv[cc];
    }
    const int wid = t >> 6, lane = t & 63;
    #pragma unroll
    for (int cc = 0; cc < 4; ++cc) {
        int v = act ? sv[cc] : 0;
        long long q = (long long)v * v;
        wred_i(v, q);
        if (lane == 0) {
            size_t pslot = (size_t)(co0 + cc) * 320 + bg * 5 + wid;
            part[pslot * 2]     = (double)v;
            part[pslot * 2 + 1] = (double)q;
        }
    }
}

// ---------------------------------------------------------------------------
// conv5 (NW=4, single chunk) + in-LDS maxpool3x3/2 + per-wave stats on POOLED.
// CO=4. grid (64, 64).
// ---------------------------------------------------------------------------
__global__ __launch_bounds__(320)
void k_conv5(const u64* __restrict__ ps, const u64* __restrict__ zap,
             const u64* __restrict__ w, float* __restrict__ outp,
             double* __restrict__ part, const ushort* __restrict__ tP,
             const int* __restrict__ wflags, const int* __restrict__ bz) {
    __shared__ u64 st_s[4 * 576];
    __shared__ int sacc[4][288];
    __shared__ int sbz[8];
    const int co0 = blockIdx.x * 4, bg = blockIdx.y, b0 = bg * 8, t = threadIdx.x;
    const int wfl = wflags[3];
    if (t < 8) sbz[t] = bz[b0 + t];
    const bool act = t < 288;
    const int bb = act ? t / 36 : 0, r = act ? t - (t / 36) * 36 : 0;
    const int y = r / 6, x0 = r - y * 6;
    for (int i = t; i < 4 * 576; i += 320) st_s[i] = 0;
    __syncthreads();
    for (int i = t; i < 8 * 36 * 4; i += 320) {
        int wd = i % 4, j = (i / 4) % 36, bb2 = i / 144;
        int yy = j / 6, xx = j - yy * 6;
        st_s[wd * 576 + bb2 * 72 + (yy + 1) * 9 + xx + 1] =
            ps[((size_t)(b0 + bb2) * 36 + j) * 4 + wd];
    }
    __syncthreads();
    int S[4] = {0, 0, 0, 0};
    if (act && wfl == 0) {
        #pragma unroll
        for (int ky = 0; ky < 3; ++ky)
            #pragma unroll
            for (int kx = 0; kx < 3; ++kx) {
                const int vb = bb * 72 + (y + ky) * 9 + x0 + kx;
                #pragma unroll
                for (int wd = 0; wd < 4; ++wd) {
                    u64 a = st_s[wd * 576 + vb];
                    #pragma unroll
                    for (int cc = 0; cc < 4; ++cc) {
                        u64 ws_ = w[((size_t)(co0 + cc) * 9 + ky * 3 + kx) * 8 + 2 * wd];
                        S[cc] += (int)__popcll(a ^ ws_);
                    }
                }
            }
    }
    if (act) {
        int sv[4];
        if (wfl == 0) {
            const int ky0 = (y == 0), ky1 = (y == 5) ? 2 : 3;
            const int kx0 = (x0 == 0), kx1 = (x0 == 5) ? 2 : 3;
            const int nv = (ky1 - ky0) * (kx1 - kx0);
            #pragma unroll
            for (int cc = 0; cc < 4; ++cc) {
                const ushort* tb = tP + (co0 + cc) * 16;
                int Wt = tb[15];
                int Wr = (int)tb[ky1 * 4 + kx1] - (int)tb[ky0 * 4 + kx1]
                       - (int)tb[ky1 * 4 + kx0] + (int)tb[ky0 * 4 + kx0];
                sv[cc] = 256 * nv - 2 * S[cc] + 2 * (Wt - Wr);
            }
            if (sbz[bb]) {
                #pragma unroll 1
                for (int ky = 0; ky < 3; ++ky) {
                    int yy = y - 1 + ky;
                    if ((unsigned)yy >= 6u) continue;
                    #pragma unroll 1
                    for (int kx = 0; kx < 3; ++kx) {
                        int xx = x0 - 1 + kx;
                        if ((unsigned)xx >= 6u) continue;
                        size_t g = ((size_t)(b0 + bb) * 36 + yy * 6 + xx) * 4;
                        #pragma unroll 1
                        for (int wd = 0; wd < 4; ++wd) {
                            u64 za = zap[g + wd];
                            if (za) {
                                int pz = (int)__popcll(za);
                                #pragma unroll
                                for (int cc = 0; cc < 4; ++cc) {
                                    u64 ws_ = w[((size_t)(co0 + cc) * 9 + ky * 3 + kx) * 8 + 2 * wd];
                                    sv[cc] += 2 * (int)__popcll(ws_ & za) - pz;
                                }
                            }
                        }
                    }
                }
            }
        } else {
            #pragma unroll 1
            for (int cc = 0; cc < 4; ++cc) {
                const u64* wb = w + (size_t)(co0 + cc) * 72;
                int sum = 0;
                for (int ky = 0; ky < 3; ++ky) {
                    int yy = y - 1 + ky;
                    if ((unsigned)yy >= 6u) continue;
                    for (int kx = 0; kx < 3; ++kx) {
                        int xx = x0 - 1 + kx;
                        if ((unsigned)xx >= 6u) continue;
                        size_t g = ((size_t)(b0 + bb) * 36 + yy * 6 + xx) * 4;
                        const u64* wp = wb + (ky * 3 + kx) * 8;
                        for (int wd = 0; wd < 4; ++wd) {
                            u64 val = ~zap[g + wd] & wp[2 * wd + 1];
                            u64 df  = (ps[g + wd] ^ wp[2 * wd]) & val;
                            sum += (int)__popcll(val) - 2 * (int)__popcll(df);
                        }
                    }
                }
                sv[cc] = sum;
            }
        }
        #pragma unroll
        for (int cc = 0; cc < 4; ++cc)
            sacc[cc][bb * 36 + r] = sv[cc];
    }
    __syncthreads();
    int pooled[4] = {0, 0, 0, 0};
    const bool pact = t < 32;
    if (pact) {
        int bb2 = t / 4, wi = t % 4, py = (wi >> 1) * 2, px = (wi & 1) * 2;
        #pragma unroll
        for (int cc = 0; cc < 4; ++cc) {
            int best = -1000000;
            #pragma unroll
            for (int dy = 0; dy < 3; ++dy)
                #pragma unroll
                for (int dx = 0; dx < 3; ++dx)
                    best = max(best, sacc[cc][bb2 * 36 + (py + dy) * 6 + (px + dx)]);
            pooled[cc] = best;
            outp[((size_t)(b0 + bb2) * 256 + co0 + cc) * 4 + wi] = (float)best;
        }
    }
    const int wid = t >> 6, lane = t & 63;
    #pragma unroll
    for (int cc = 0; cc < 4; ++cc) {
        int v = pact ? pooled[cc] : 0;
        long long q = (long long)v * v;
        wred_i(v, q);
        if (lane == 0) {
            size_t pslot = (size_t)(co0 + cc) * 320 + bg * 5 + wid;
            part[pslot * 2]     = (double)v;
            part[pslot * 2 + 1] = (double)q;
        }
    }
}

// ---------------------------------------------------------------------------
__global__ void k_stats_final(const double* __restrict__ part, const float* __restrict__ g,
                              float* __restrict__ mean, float* __restrict__ inva,
                              int NB, long total) {
    __shared__ double sS[64], sQ[64];
    const int c = blockIdx.x, t = threadIdx.x;
    double s = 0.0, q = 0.0;
    for (int k = t; k < NB; k += 64) {
        s += part[((size_t)c * NB + k) * 2];
        q += part[((size_t)c * NB + k) * 2 + 1];
    }
    sS[t] = s; sQ[t] = q;
    __syncthreads();
    for (int o = 32; o > 0; o >>= 1) {
        if (t < o) { sS[t] += sS[t + o]; sQ[t] += sQ[t + o]; }
        __syncthreads();
    }
    if (t == 0) {
        double m = sS[0] / (double)total;
        double var = sQ[0] / (double)total - m * m;
        mean[c] = (float)m;
        inva[c] = g[c] * (float)(1.0 / sqrt(var + 1e-5));
    }
}

// ---- BN apply + sign + pack -> sign plane, za plane, per-batch zero flags ----
__global__ void k_bnpack2d(const float* __restrict__ x, const float* __restrict__ m,
                           const float* __restrict__ a, const float* __restrict__ bt,
                           u64* __restrict__ ps, u64* __restrict__ za,
                           int B, int C, int HW, int* __restrict__ bz) {
    int NW = C >> 6;
    int tot = B * HW * NW;
    int idx = blockIdx.x * blockDim.x + threadIdx.x;
    if (idx >= tot) return;
    int wd = idx % NW, t = idx / NW;
    int j = t % HW, b = t / HW;
    u64 s = 0, nz = 0;
    for (int c0 = 0; c0 < 64; ++c0) {
        int c = wd * 64 + c0;
        float v = (x[((size_t)b * C + c) * HW + j] - m[c]) * a[c] + bt[c];
        if (v > 0.0f) s |= (1ull << c0);
        if (v != 0.0f) nz |= (1ull << c0);
    }
    size_t o = ((size_t)b * HW + j) * NW + wd;
    ps[o] = s; za[o] = ~nz;
    if (nz != ~0ull) atomicOr(bz + b, 1);
}

__global__ void k_bnpack_flat(const float* __restrict__ x, const float* __restrict__ m,
                              const float* __restrict__ a, const float* __restrict__ bt,
                              u64* __restrict__ ps, u64* __restrict__ za,
                              int B, int* __restrict__ bz) {
    int idx = blockIdx.x * blockDim.x + threadIdx.x;
    if (idx >= B * 16) return;
    int wd = idx % 16, b = idx / 16;
    u64 s = 0, nz = 0;
    for (int k = 0; k < 64; ++k) {
        int f = wd * 64 + k;
        int c = f >> 2, j = f & 3;
        float v = (x[((size_t)b * 256 + c) * 4 + j] - m[c]) * a[c] + bt[c];
        if (v > 0.0f) s |= (1ull << k);
        if (v != 0.0f) nz |= (1ull << k);
    }
    ps[(size_t)b * 16 + wd] = s;
    za[(size_t)b * 16 + wd] = ~nz;
    if (nz != ~0ull) atomicOr(bz + b, 1);
}

__global__ void k_bnpack1d(const float* __restrict__ x, const float* __restrict__ m,
                           const float* __restrict__ a, const float* __restrict__ bt,
                           u64* __restrict__ ps, u64* __restrict__ za,
                           int B, int F, int* __restrict__ bz) {
    int NW = F >> 6;
    int idx = blockIdx.x * blockDim.x + threadIdx.x;
    if (idx >= B * NW) return;
    int wd = idx % NW, b = idx / NW;
    const float* row = x + (size_t)b * F + wd * 64;
    u64 s = 0, nz = 0;
    for (int c = 0; c < 64; ++c) {
        int f = wd * 64 + c;
        float v = (row[c] - m[f]) * a[f] + bt[f];
        if (v > 0.0f) s |= (1ull << c);
        if (v != 0.0f) nz |= (1ull << c);
    }
    ps[(size_t)b * NW + wd] = s;
    za[(size_t)b * NW + wd] = ~nz;
    if (nz != ~0ull) atomicOr(bz + b, 1);
}

// ---------------------------------------------------------------------------
// binary FC, 32x32 tile, 2x2 micro-tile, sign-only LDS, row zero-correction.
// ---------------------------------------------------------------------------
template<int NW>
__global__ __launch_bounds__(256)
void k_fcbin3(const u64* __restrict__ As_, const u64* __restrict__ zaA,
              const u64* __restrict__ Ws_, const u64* __restrict__ Wn_,
              const float* __restrict__ bias, float* __restrict__ C, int O,
              double* __restrict__ part, int nbc, const int* __restrict__ wflags,
              int slot, const int* __restrict__ rowz) {
    constexpr int ST = NW | 1;
    __shared__ u64 sA[32 * ST];
    __shared__ u64 sW[32 * ST];
    __shared__ int sacc[32][32];
    __shared__ int srz[32];
    const int t = threadIdx.x;
    const int wfl = wflags[slot];
    const int b0 = blockIdx.y * 32, o0 = blockIdx.x * 32;
    if (t < 32) srz[t] = rowz[b0 + t];
    for (int i = t; i < 32 * NW; i += 256) {
        int rr = i / NW, cc = i % NW;
        sA[rr * ST + cc] = As_[(size_t)(b0 + rr) * NW + cc];
        int o = o0 + rr;
        sW[rr * ST + cc] = (o < O) ? Ws_[(size_t)o * NW + cc] : 0ull;
    }
    __syncthreads();
    const int tx = t % 16, ty = t / 16;
    int acc[2][2];
    if (wfl == 0) {
        int S00 = 0, S01 = 0, S10 = 0, S11 = 0;
        #pragma unroll
        for (int wd = 0; wd < NW; ++wd) {
            u64 a0 = sA[ty * ST + wd], a1 = sA[(16 + ty) * ST + wd];
            u64 w0 = sW[tx * ST + wd], w1 = sW[(16 + tx) * ST + wd];
            S00 += (int)__popcll(a0 ^ w0); S01 += (int)__popcll(a0 ^ w1);
            S10 += (int)__popcll(a1 ^ w0); S11 += (int)__popcll(a1 ^ w1);
        }
        acc[0][0] = 64 * NW - 2 * S00; acc[0][1] = 64 * NW - 2 * S01;
        acc[1][0] = 64 * NW - 2 * S10; acc[1][1] = 64 * NW - 2 * S11;
        #pragma unroll
        for (int i = 0; i < 2; ++i) {
            if (srz[ty + 16 * i]) {
                int b = b0 + ty + 16 * i;
                int c0_ = 0, c1_ = 0;
                #pragma unroll 1
                for (int wd = 0; wd < NW; ++wd) {
                    u64 za = zaA[(size_t)b * NW + wd];
                    if (za) {
                        int pz = (int)__popcll(za);
                        c0_ += 2 * (int)__popcll(sW[tx * ST + wd] & za) - pz;
                        c1_ += 2 * (int)__popcll(sW[(16 + tx) * ST + wd] & za) - pz;
                    }
                }
                acc[i][0] += c0_;
                acc[i][1] += c1_;
            }
        }
    } else {
        #pragma unroll 1
        for (int i = 0; i < 2; ++i)
            #pragma unroll 1
            for (int j = 0; j < 2; ++j) {
                int b = b0 + ty + 16 * i, o = o0 + tx + 16 * j;
                int aV = 0, aD = 0;
                if (o < O) {
                    for (int wd = 0; wd < NW; ++wd) {
                        u64 val = ~zaA[(size_t)b * NW + wd] & Wn_[(size_t)o * NW + wd];
                        u64 df  = (As_[(size_t)b * NW + wd] ^ Ws_[(size_t)o * NW + wd]) & val;
                        aV += (int)__popcll(val); aD += (int)__popcll(df);
                    }
                }
                acc[i][j] = aV - 2 * aD;
            }
    }
    #pragma unroll
    for (int i = 0; i < 2; ++i)
        #pragma unroll
        for (int j = 0; j < 2; ++j) {
            int o = o0 + tx + 16 * j;
            int v = (o < O) ? acc[i][j] : 0;
            if (o < O)
                C[(size_t)(b0 + ty + 16 * i) * O + o] = (float)v + (bias ? bias[o] : 0.0f);
            sacc[ty + 16 * i][tx + 16 * j] = v;
        }
    __syncthreads();
    if (part != nullptr && t < 32) {
        int s = 0; long long q = 0;
        #pragma unroll
        for (int b = 0; b < 32; ++b) {
            int v = sacc[b][t];
            s += v; q += (long long)v * v;
        }
        if (o0 + t < O) {
            part[((size_t)(o0 + t) * nbc + blockIdx.y) * 2]     = (double)s;
            part[((size_t)(o0 + t) * nbc + blockIdx.y) * 2 + 1] = (double)q;
        }
    }
}

// ---------------------------------------------------------------------------

static inline int cdiv(long a, int b) { return (int)((a + b - 1) / b); }

extern "C" void kernel_launch(void* const* d_in, const int* in_sizes, int n_in,
                              void* d_out, int out_size, void* d_ws, size_t ws_size,
                              hipStream_t stream) {
    const float* x   = (const float*)d_in[0];
    const float* w1  = (const float*)d_in[1];
    const float* g1  = (const float*)d_in[2];
    const float* b1  = (const float*)d_in[3];
    const float* w2  = (const float*)d_in[4];
    const float* g2  = (const float*)d_in[5];
    const float* b2  = (const float*)d_in[6];
    const float* w3  = (const float*)d_in[7];
    const float* g3  = (const float*)d_in[8];
    const float* b3  = (const float*)d_in[9];
    const float* w4  = (const float*)d_in[10];
    const float* g4  = (const float*)d_in[11];
    const float* b4  = (const float*)d_in[12];
    const float* w5  = (const float*)d_in[13];
    const float* g5  = (const float*)d_in[14];
    const float* b5  = (const float*)d_in[15];
    const float* wl1 = (const float*)d_in[16];
    const float* gl1 = (const float*)d_in[17];
    const float* bl1 = (const float*)d_in[18];
    const float* wl2 = (const float*)d_in[19];
    const float* gl2 = (const float*)d_in[20];
    const float* bl2 = (const float*)d_in[21];
    const float* wl3 = (const float*)d_in[22];
    const float* bl3 = (const float*)d_in[23];
    float* out = (float*)d_out;
    (void)in_sizes; (void)n_in; (void)out_size; (void)ws_size;

    char* base = (char*)d_ws;
    size_t off = 0;
    auto alloc = [&](size_t bytes) {
        char* p = base + off;
        off += (bytes + 15) & ~(size_t)15;
        return (void*)p;
    };
    float* R1   = (float*)alloc(7372800 * 4);
    float* R2   = (float*)alloc(4718592 * 4);
    float* R3   = (float*)alloc(524288 * 4);
    float* w1s  = (float*)alloc(4800 * 4);
    u64* p1s = (u64*)alloc(115200 * 8);   u64* p1z = (u64*)alloc(115200 * 8);
    u64* p2s = (u64*)alloc(55296 * 8);    u64* p2z = (u64*)alloc(55296 * 8);
    u64* p3s = (u64*)alloc(110592 * 8);   u64* p3z = (u64*)alloc(110592 * 8);
    u64* p4s = (u64*)alloc(73728 * 8);    u64* p4z = (u64*)alloc(73728 * 8);
    u64* p5s = (u64*)alloc(8192 * 8);     u64* p5z = (u64*)alloc(8192 * 8);
    u64* pf1s = (u64*)alloc(32768 * 8);   u64* pf1z = (u64*)alloc(32768 * 8);
    u64* pf2s = (u64*)alloc(16384 * 8);   u64* pf2z = (u64*)alloc(16384 * 8);
    u64* w2p  = (u64*)alloc(9600 * 8);
    u64* w3p  = (u64*)alloc(20736 * 8);
    u64* w4p  = (u64*)alloc(27648 * 8);
    u64* w5p  = (u64*)alloc(18432 * 8);
    u64* wl1s_ = (u64*)alloc(65536 * 8);  u64* wl1n_ = (u64*)alloc(65536 * 8);
    u64* wl2s_ = (u64*)alloc(131072 * 8); u64* wl2n_ = (u64*)alloc(131072 * 8);
    u64* wl3s_ = (u64*)alloc(320 * 8);    u64* wl3n_ = (u64*)alloc(320 * 8);
    double* part = (double*)alloc((size_t)131072 * 2 * 8);   // max: conv1 64ch x 2048 slots
    float* stats = (float*)alloc(7 * 2 * 4096 * 4);
    int* wflags = (int*)alloc((8 + 7 * 512) * 4);
    int* bzc2 = wflags + 8;
    int* bzc3 = bzc2 + 512;
    int* bzc4 = bzc3 + 512;
    int* bzc5 = bzc4 + 512;
    int* rz1  = bzc5 + 512;
    int* rz2  = rz1 + 512;
    int* rz3  = rz2 + 512;
    ushort* t2 = (ushort*)alloc(192 * 4 * 2);
    ushort* t3 = (ushort*)alloc(384 * 16 * 2);
    ushort* t4 = (ushort*)alloc(256 * 16 * 2);
    ushort* t5 = (ushort*)alloc(256 * 16 * 2);
    float* m_[7]; float* a_[7];
    for (int l = 0; l < 7; ++l) { m_[l] = stats + (size_t)l * 8192; a_[l] = m_[l] + 4096; }

    hipMemsetAsync(wflags, 0, (8 + 7 * 512) * 4, stream);

    // ---- weight prep ----
    k_prep<<<cdiv(PREP_TOTAL, 256), 256, 0, stream>>>(
        w1, w1s, w2, w2p, w3, w3p, w4, w4p, w5, w5p,
        wl1, wl1s_, wl1n_, wl2, wl2s_, wl2n_, wl3, wl3s_, wl3n_, wflags);
    k_prep2<<<cdiv(192 + 384 + 256 + 256, 256), 256, 0, stream>>>(
        w2p, w3p, w4p, w5p, t2, t3, t4, t5);

    // ---- conv1 + pool -> R1 (+stats); bn1; pack -> p1 ----
    k_conv1<<<dim3(8, 512), 256, 0, stream>>>(x, w1s, R1, part);
    k_stats_final<<<64, 64, 0, stream>>>(part, g1, m_[0], a_[0], 2048, (long)512 * 225);
    k_bnpack2d<<<cdiv((long)512 * 225, 256), 256, 0, stream>>>(R1, m_[0], a_[0], b1, p1s, p1z, 512, 64, 225, bzc2);

    // ---- conv2 (CO=4) + pool -> R2 (+stats); bn2; pack -> p2 ----
    k_conv2<<<dim3(48, 64), 320, 0, stream>>>(p1s, p1z, w2p, R2, part, t2, wflags, bzc2);
    k_stats_final<<<192, 64, 0, stream>>>(part, g2, m_[1], a_[1], 320, (long)512 * 36);
    k_bnpack2d<<<cdiv((long)512 * 36 * 3, 256), 256, 0, stream>>>(R2, m_[1], a_[1], b2, p2s, p2z, 512, 192, 36, bzc3);

    // ---- conv3 (CO=4) -> R1 (+stats); bn3; pack -> p3 ----
    k_convbin3<3, 3><<<dim3(96, 64), 320, 0, stream>>>(p2s, p2z, w3p, R1, part, 384, t3, wflags, 1, bzc3);
    k_stats_final<<<384, 64, 0, stream>>>(part, g3, m_[2], a_[2], 320, (long)512 * 36);
    k_bnpack2d<<<cdiv((long)512 * 36 * 6, 256), 256, 0, stream>>>(R1, m_[2], a_[2], b3, p3s, p3z, 512, 384, 36, bzc4);

    // ---- conv4 (CO=4, single chunk NWC=6) -> R2 (+stats); bn4; pack -> p4 ----
    k_convbin3<6, 6><<<dim3(64, 64), 320, 0, stream>>>(p3s, p3z, w4p, R2, part, 256, t4, wflags, 2, bzc4);
    k_stats_final<<<256, 64, 0, stream>>>(part, g4, m_[3], a_[3], 320, (long)512 * 36);
    k_bnpack2d<<<cdiv((long)512 * 36 * 4, 256), 256, 0, stream>>>(R2, m_[3], a_[3], b4, p4s, p4z, 512, 256, 36, bzc5);

    // ---- conv5 (CO=4, single chunk) + in-LDS pool -> R3 (+stats); bn5; pack -> p5 ----
    k_conv5<<<dim3(64, 64), 320, 0, stream>>>(p4s, p4z, w5p, R3, part, t5, wflags, bzc5);
    k_stats_final<<<256, 64, 0, stream>>>(part, g5, m_[4], a_[4], 320, (long)512 * 4);
    k_bnpack_flat<<<cdiv(512 * 16, 256), 256, 0, stream>>>(R3, m_[4], a_[4], b5, p5s, p5z, 512, rz1);

    // ---- fc1 -> R2 (+stats); bn; pack -> pf1 ----
    k_fcbin3<16><<<dim3(128, 16), 256, 0, stream>>>(p5s, p5z, wl1s_, wl1n_, nullptr, R2, 4096, part, 16, wflags, 4, rz1);
    k_stats_final<<<4096, 64, 0, stream>>>(part, gl1, m_[5], a_[5], 16, 512);
    k_bnpack1d<<<cdiv(512 * 64, 256), 256, 0, stream>>>(R2, m_[5], a_[5], bl1, pf1s, pf1z, 512, 4096, rz2);

    // ---- fc2 -> R1 (+stats); bn; pack -> pf2 ----
    k_fcbin3<64><<<dim3(64, 16), 256, 0, stream>>>(pf1s, pf1z, wl2s_, wl2n_, nullptr, R1, 2048, part, 16, wflags, 5, rz2);
    k_stats_final<<<2048, 64, 0, stream>>>(part, gl2, m_[6], a_[6], 16, 512);
    k_bnpack1d<<<cdiv(512 * 32, 256), 256, 0, stream>>>(R1, m_[6], a_[6], bl2, pf2s, pf2z, 512, 2048, rz3);

    // ---- fc3 + bias -> out [512,10] ----
    k_fcbin3<32><<<dim3(1, 16), 256, 0, stream>>>(pf2s, pf2z, wl3s_, wl3n_, bl3, out, 10, nullptr, 0, wflags, 6, rz3);
}